// Round 5
// baseline (232.481 us; speedup 1.0000x reference)
//
#include <hip/hip_runtime.h>

// PQN soft-quantization: x[32768,1024] f32, c[1024,256] f32 -> out[32768,1024] f32
// D=1024, M=8 subspaces of L=128, K=256 codes, logits scaled by 2*ALPHA=20.
//
// 32x32x16 f16 MFMA pipeline. One block per CU (128 KB LDS), 8 waves, 2/SIMD,
// VGPR budget forced to 256 via amdgpu_waves_per_eu(2) (default heuristic caps
// at 128 -> ~90 regs of spill; rounds 2/4 showed the spill traffic on HBM).
// Each wave-iter handles 32 samples:
//   phase 1: z^T[256 codes][32 samples] = cs^T . x^T   (A from LDS csA, B = x in regs)
//   softmax: per-lane (each lane owns 1 sample's 128 codes) + one xor-32 shuffle
//   phase 2: out^T[128 l][32 samples] = cs . w^T       (A from LDS csB, B = packed w)
// P-transpose for phase 2 = 2 x v_permlane32_swap per k-step (no LDS, no bpermute).
// Next-iter x prefetch sits AFTER the P-pack so it never overlaps acc[8] (peak
// live ~210 regs: P 64 + acc2 64 + xa 64 + temps).

#define D_  1024
#define K_  256
#define L_  128

typedef _Float16 f16;
typedef f16 f16x8 __attribute__((ext_vector_type(8)));
typedef f16 f16x4 __attribute__((ext_vector_type(4)));
typedef f16 f16x2 __attribute__((ext_vector_type(2)));
typedef float f32x4  __attribute__((ext_vector_type(4)));
typedef float f32x16 __attribute__((ext_vector_type(16)));
typedef unsigned int u32;

__global__ __attribute__((amdgpu_flat_work_group_size(512, 512), amdgpu_waves_per_eu(2)))
void pqn_kernel(const float* __restrict__ x, const float* __restrict__ c,
                float* __restrict__ out) {
    __shared__ unsigned char lds[131072];
    unsigned char* csA = lds;          // [256 codes][128 l] f16, 256 B rows, swz ^=(code&7)<<4
    unsigned char* csB = lds + 65536;  // [128 l][256 codes] f16, 512 B rows, swz ^=(l&7)<<4

    const int tid  = threadIdx.x;
    const int m    = blockIdx.x >> 5;   // 8 subspaces
    const int bm   = blockIdx.x & 31;   // 32 blocks per subspace
    const int lane = tid & 63;
    const int w    = tid >> 6;          // wave 0..7
    const int n32  = lane & 31;         // sample column
    const int h    = lane >> 5;         // half-wave

    // x fragment loads: lane (n32,h) holds row (r0+n32), bytes [64k+32h, +32) per k.
    // Issue the first tile's loads BEFORE staging so HBM latency hides under it.
    const float* xbase = x + (size_t)(bm * 1024 + w * 32 + n32) * D_ + m * L_ + h * 8;
    float4 xa[16];
    {
        const float* p = xbase;
        #pragma unroll
        for (int k = 0; k < 8; ++k) {
            xa[2 * k]     = *reinterpret_cast<const float4*>(p + k * 16);
            xa[2 * k + 1] = *reinterpret_cast<const float4*>(p + k * 16 + 4);
        }
    }

    // ---------------- stage codebook subspace m into LDS (f16, both layouts) -------------
    const float* cm = c + (size_t)m * L_ * K_;      // cm[l*256 + k]
    {
        const int R0 = tid >> 6;        // 0..7
        const int f  = tid & 63;        // code quad index
        #pragma unroll
        for (int b = 0; b < 8; ++b) {
            int R  = b * 8 + R0;        // 0..63
            int l0 = 2 * R;             // even row
            float4 a  = *reinterpret_cast<const float4*>(cm + (size_t)l0 * K_ + 4 * f);
            float4 bb = *reinterpret_cast<const float4*>(cm + (size_t)(l0 + 1) * K_ + 4 * f);
            f16x4 va = {(f16)a.x, (f16)a.y, (f16)a.z, (f16)a.w};
            f16x4 vb = {(f16)bb.x, (f16)bb.y, (f16)bb.z, (f16)bb.w};
            *reinterpret_cast<f16x4*>(csB + l0 * 512       + ((8 * f) ^ ((l0 & 7) << 4))) = va;
            *reinterpret_cast<f16x4*>(csB + (l0 + 1) * 512 + ((8 * f) ^ (((l0 + 1) & 7) << 4))) = vb;
            #pragma unroll
            for (int j = 0; j < 4; ++j) {
                int code = 4 * f + j;
                f16x2 t = { va[j], vb[j] };   // elements l0, l0+1 of row `code`
                *reinterpret_cast<f16x2*>(csA + code * 256 + ((4 * R) ^ ((code & 7) << 4))) = t;
            }
        }
    }
    __syncthreads();

    for (int it = 0; it < 4; ++it) {
        const int r0 = bm * 1024 + it * 256 + w * 32;

        // ---- norm partial (this lane's 64 floats of its row) + B1 fragments ----
        float ss = 0.f;
        f16x8 bf[8];
        #pragma unroll
        for (int k = 0; k < 8; ++k) {
            float4 lo = xa[2 * k], hi = xa[2 * k + 1];
            ss = fmaf(lo.x, lo.x, ss); ss = fmaf(lo.y, lo.y, ss);
            ss = fmaf(lo.z, lo.z, ss); ss = fmaf(lo.w, lo.w, ss);
            ss = fmaf(hi.x, hi.x, ss); ss = fmaf(hi.y, hi.y, ss);
            ss = fmaf(hi.z, hi.z, ss); ss = fmaf(hi.w, hi.w, ss);
            bf[k][0] = (f16)lo.x; bf[k][1] = (f16)lo.y;
            bf[k][2] = (f16)lo.z; bf[k][3] = (f16)lo.w;
            bf[k][4] = (f16)hi.x; bf[k][5] = (f16)hi.y;
            bf[k][6] = (f16)hi.z; bf[k][7] = (f16)hi.w;
        }
        ss += __shfl_xor(ss, 32);                       // full-row sum of squares
        const float fac = 20.0f / fmaxf(sqrtf(ss), 1e-12f);

        // ---- phase 1: acc[ct] = z^T[ct*32+row32][n32], row32=(r&3)+8(r>>2)+4h ----
        f32x16 acc[8];
        #pragma unroll
        for (int ct = 0; ct < 8; ++ct) acc[ct] = (f32x16)(0.f);
        #pragma unroll
        for (int ks = 0; ks < 8; ++ks) {
            #pragma unroll
            for (int ct = 0; ct < 8; ++ct) {
                f16x8 af = *reinterpret_cast<const f16x8*>(
                    csA + (ct * 32 + n32) * 256 + ((ks * 32 + h * 16) ^ ((n32 & 7) << 4)));
                acc[ct] = __builtin_amdgcn_mfma_f32_32x32x16_f16(af, bf[ks], acc[ct], 0, 0, 0);
            }
        }

        // ---- softmax over 256 codes: each lane owns sample n32's 128 codes ----
        float z0 = -3.0e38f, z1 = -3.0e38f, z2 = -3.0e38f, z3 = -3.0e38f;
        #pragma unroll
        for (int ct = 0; ct < 8; ++ct) {
            #pragma unroll
            for (int e = 0; e < 4; ++e) {
                z0 = fmaxf(z0, acc[ct][4 * e + 0]);
                z1 = fmaxf(z1, acc[ct][4 * e + 1]);
                z2 = fmaxf(z2, acc[ct][4 * e + 2]);
                z3 = fmaxf(z3, acc[ct][4 * e + 3]);
            }
        }
        float zm = fmaxf(fmaxf(z0, z1), fmaxf(z2, z3));
        zm = fmaxf(zm, __shfl_xor(zm, 32));             // other half of codes
        const float nfz = -fac * zm;

        float s0 = 0.f, s1 = 0.f, s2 = 0.f, s3 = 0.f;
        #pragma unroll
        for (int ct = 0; ct < 8; ++ct) {
            #pragma unroll
            for (int e = 0; e < 4; ++e) {
                float p0 = __expf(fmaf(acc[ct][4 * e + 0], fac, nfz));
                float p1 = __expf(fmaf(acc[ct][4 * e + 1], fac, nfz));
                float p2 = __expf(fmaf(acc[ct][4 * e + 2], fac, nfz));
                float p3 = __expf(fmaf(acc[ct][4 * e + 3], fac, nfz));
                acc[ct][4 * e + 0] = p0; acc[ct][4 * e + 1] = p1;
                acc[ct][4 * e + 2] = p2; acc[ct][4 * e + 3] = p3;
                s0 += p0; s1 += p1; s2 += p2; s3 += p3;
            }
        }
        float S = (s0 + s1) + (s2 + s3);
        S += __shfl_xor(S, 32);
        const float invS = 1.0f / S;

        // ---- pack unnormalized weights to f16 pairs: P[ct][e] = (p[2e], p[2e+1]) ----
        u32 P[8][8];
        #pragma unroll
        for (int ct = 0; ct < 8; ++ct) {
            #pragma unroll
            for (int e = 0; e < 8; ++e) {
                P[ct][e] = __builtin_bit_cast(
                    u32, __builtin_amdgcn_cvt_pkrtz(acc[ct][2 * e], acc[ct][2 * e + 1]));
            }
        }

        // ---- prefetch next iter's x (acc[] is dead now; overlaps phase 2) ----
        if (it < 3) {
            const float* p = xbase + (size_t)(it + 1) * 256 * D_;
            #pragma unroll
            for (int k = 0; k < 8; ++k) {
                xa[2 * k]     = *reinterpret_cast<const float4*>(p + k * 16);
                xa[2 * k + 1] = *reinterpret_cast<const float4*>(p + k * 16 + 4);
            }
        }

        // ---- phase 2: out^T[l][n32] = cs . w^T ----
        f32x16 acc2[4];
        #pragma unroll
        for (int lt = 0; lt < 4; ++lt) acc2[lt] = (f32x16)(0.f);
        #pragma unroll
        for (int ks16 = 0; ks16 < 16; ++ks16) {
            const int ct = ks16 >> 1;
            const int eb = 4 * (ks16 & 1);
            // build B fragment: pb[i] = w[ks16*16 + h*8 + i][n32]
            u32 a0 = P[ct][eb + 0], b0 = P[ct][eb + 2];
            u32 a1 = P[ct][eb + 1], b1 = P[ct][eb + 3];
            asm("v_permlane32_swap_b32 %0, %1" : "+v"(a0), "+v"(b0));
            asm("v_permlane32_swap_b32 %0, %1" : "+v"(a1), "+v"(b1));
            union { f16x8 v; u32 q[4]; } pb;
            pb.q[0] = a0; pb.q[1] = a1; pb.q[2] = b0; pb.q[3] = b1;
            #pragma unroll
            for (int lt = 0; lt < 4; ++lt) {
                f16x8 a2 = *reinterpret_cast<const f16x8*>(
                    csB + (lt * 32 + n32) * 512 + ((ks16 * 32 + h * 16) ^ ((n32 & 7) << 4)));
                acc2[lt] = __builtin_amdgcn_mfma_f32_32x32x16_f16(a2, pb.v, acc2[lt], 0, 0, 0);
            }
        }

        // ---- store: l = lt*32 + 8q + 4h + {0..3}, row r0+n32 ----
        float* po = out + (size_t)(r0 + n32) * D_ + m * L_ + h * 4;
        #pragma unroll
        for (int lt = 0; lt < 4; ++lt) {
            #pragma unroll
            for (int q = 0; q < 4; ++q) {
                f32x4 v;
                v[0] = acc2[lt][4 * q + 0] * invS;
                v[1] = acc2[lt][4 * q + 1] * invS;
                v[2] = acc2[lt][4 * q + 2] * invS;
                v[3] = acc2[lt][4 * q + 3] * invS;
                __builtin_nontemporal_store(v,
                    reinterpret_cast<f32x4*>(po + lt * 32 + 8 * q));
            }
        }
    }
}

extern "C" void kernel_launch(void* const* d_in, const int* in_sizes, int n_in,
                              void* d_out, int out_size, void* d_ws, size_t ws_size,
                              hipStream_t stream) {
    const float* x = (const float*)d_in[0];   // [32768, 1024] f32
    const float* c = (const float*)d_in[1];   // [1024, 256]   f32
    float* out = (float*)d_out;               // [32768, 1024] f32
    (void)in_sizes; (void)n_in; (void)out_size; (void)d_ws; (void)ws_size;

    pqn_kernel<<<dim3(256), dim3(512), 0, stream>>>(x, c, out);
}